// Round 1
// baseline (853.264 us; speedup 1.0000x reference)
//
#include <hip/hip_runtime.h>
#include <stdint.h>

// Soft Decision Tree forward, MI355X
// Pass A: p = sigmoid([1,X] @ W_inner^T)  -> bf16 in ws   (f32 SGEMM baseline)
// Pass B: tree sweep -> y_pred, leaf sums
// Pass C: penalty from leaf sums

#define BROWS 32768
#define KDIM  784
#define NNODE 1023
#define NP    1024   // padded p stride
#define NLEAF 1024
#define OUTD  10
#define NDEPTH 10
#define LAMDA 1e-3f

__device__ __forceinline__ unsigned short f2bf(float f) {
    unsigned int u = __float_as_uint(f);
    u = u + 0x7FFFu + ((u >> 16) & 1u);   // RNE; p in (0,1), no NaN/Inf
    return (unsigned short)(u >> 16);
}
__device__ __forceinline__ float bf2f(unsigned short h) {
    return __uint_as_float(((unsigned int)h) << 16);
}

// ---------------- Pass A: SGEMM + sigmoid ----------------
#define BM 128
#define BN 128
#define BK 16
#define LDT 132   // padded LDS leading dim (16B-aligned rows, low bank conflict)

__global__ __launch_bounds__(256)
void sdt_gemm(const float* __restrict__ X, const float* __restrict__ Wi,
              unsigned short* __restrict__ P)
{
    __shared__ float As[BK][LDT];
    __shared__ float Bs[BK][LDT];
    const int tid = threadIdx.x;
    const int tx = tid & 15, ty = tid >> 4;
    const int col0 = blockIdx.x * BN;   // x = N tile (8) so consecutive blocks share X rows
    const int row0 = blockIdx.y * BM;   // y = M tile (256)
    const int lr = tid >> 2;            // 0..63
    const int lk = (tid & 3) << 2;      // 0,4,8,12

    float acc[8][8];
#pragma unroll
    for (int i = 0; i < 8; ++i)
#pragma unroll
        for (int j = 0; j < 8; ++j) acc[i][j] = 0.f;

    float4 a0, a1;
    float b0[4], b1[4];
    // prefetch k-chunk 0
    {
        a0 = *reinterpret_cast<const float4*>(&X[(size_t)(row0 + lr) * KDIM + lk]);
        a1 = *reinterpret_cast<const float4*>(&X[(size_t)(row0 + lr + 64) * KDIM + lk]);
        const int j0 = col0 + lr, j1 = col0 + lr + 64;
#pragma unroll
        for (int u = 0; u < 4; ++u) {
            b0[u] = (j0 < NNODE) ? Wi[(size_t)j0 * (KDIM + 1) + 1 + lk + u] : 0.f;
            b1[u] = (j1 < NNODE) ? Wi[(size_t)j1 * (KDIM + 1) + 1 + lk + u] : 0.f;
        }
    }

    const int NITER = KDIM / BK; // 49
    for (int it = 0; it < NITER; ++it) {
        __syncthreads();
        As[lk + 0][lr] = a0.x; As[lk + 1][lr] = a0.y;
        As[lk + 2][lr] = a0.z; As[lk + 3][lr] = a0.w;
        As[lk + 0][lr + 64] = a1.x; As[lk + 1][lr + 64] = a1.y;
        As[lk + 2][lr + 64] = a1.z; As[lk + 3][lr + 64] = a1.w;
#pragma unroll
        for (int u = 0; u < 4; ++u) {
            Bs[lk + u][lr] = b0[u];
            Bs[lk + u][lr + 64] = b1[u];
        }
        __syncthreads();
        if (it + 1 < NITER) {
            const int k0 = (it + 1) * BK;
            a0 = *reinterpret_cast<const float4*>(&X[(size_t)(row0 + lr) * KDIM + k0 + lk]);
            a1 = *reinterpret_cast<const float4*>(&X[(size_t)(row0 + lr + 64) * KDIM + k0 + lk]);
            const int j0 = col0 + lr, j1 = col0 + lr + 64;
#pragma unroll
            for (int u = 0; u < 4; ++u) {
                b0[u] = (j0 < NNODE) ? Wi[(size_t)j0 * (KDIM + 1) + 1 + k0 + lk + u] : 0.f;
                b1[u] = (j1 < NNODE) ? Wi[(size_t)j1 * (KDIM + 1) + 1 + k0 + lk + u] : 0.f;
            }
        }
#pragma unroll
        for (int k = 0; k < BK; ++k) {
            float4 aA = *reinterpret_cast<const float4*>(&As[k][ty * 8]);
            float4 aB = *reinterpret_cast<const float4*>(&As[k][ty * 8 + 4]);
            float4 bA = *reinterpret_cast<const float4*>(&Bs[k][tx * 8]);
            float4 bB = *reinterpret_cast<const float4*>(&Bs[k][tx * 8 + 4]);
            float av[8] = {aA.x, aA.y, aA.z, aA.w, aB.x, aB.y, aB.z, aB.w};
            float bv[8] = {bA.x, bA.y, bA.z, bA.w, bB.x, bB.y, bB.z, bB.w};
#pragma unroll
            for (int i = 0; i < 8; ++i)
#pragma unroll
                for (int j = 0; j < 8; ++j)
                    acc[i][j] = fmaf(av[i], bv[j], acc[i][j]);
        }
    }

    // epilogue: + bias, sigmoid, pack bf16, 16B stores
    float bias[8];
#pragma unroll
    for (int j = 0; j < 8; ++j) {
        const int col = col0 + tx * 8 + j;
        bias[j] = (col < NNODE) ? Wi[(size_t)col * (KDIM + 1)] : 0.f;
    }
#pragma unroll
    for (int i = 0; i < 8; ++i) {
        const int row = row0 + ty * 8 + i;
        unsigned int w[4];
#pragma unroll
        for (int j = 0; j < 4; ++j) {
            const float z0 = acc[i][2 * j] + bias[2 * j];
            const float z1 = acc[i][2 * j + 1] + bias[2 * j + 1];
            const float p0 = 1.f / (1.f + __expf(-z0));
            const float p1 = 1.f / (1.f + __expf(-z1));
            w[j] = (unsigned int)f2bf(p0) | ((unsigned int)f2bf(p1) << 16);
        }
        *reinterpret_cast<uint4*>(&P[(size_t)row * NP + col0 + tx * 8]) =
            make_uint4(w[0], w[1], w[2], w[3]);
    }
}

// ---------------- Pass B: tree sweep + leaf GEMV + leaf sums ----------------
// 256 threads = 4 waves; each wave handles 8 rows; block handles 32 rows.
__global__ __launch_bounds__(256)
void sdt_tree(const unsigned short* __restrict__ P, const float* __restrict__ Wl,
              float* __restrict__ Y, float* __restrict__ leafsum)
{
    __shared__ float wl[OUTD * NLEAF];  // 40 KB
    __shared__ float buf[4][NP];        // 16 KB: per-wave p row; reused as leaf-sum buf
    const int tid = threadIdx.x;
    const int wave = tid >> 6, lane = tid & 63;

    for (int idx = tid; idx < (OUTD * NLEAF) / 4; idx += 256)
        reinterpret_cast<float4*>(wl)[idx] = reinterpret_cast<const float4*>(Wl)[idx];
    __syncthreads();

    float lsum[16];
#pragma unroll
    for (int i = 0; i < 16; ++i) lsum[i] = 0.f;

    float* pl = buf[wave];
    const int rowbase = blockIdx.x * 32 + wave * 8;
    float yp[OUTD];

    for (int r = 0; r < 8; ++r) {
        const int row = rowbase + r;
        const uint4* prow = reinterpret_cast<const uint4*>(P + (size_t)row * NP);
#pragma unroll
        for (int c = 0; c < 2; ++c) {
            const uint4 v = prow[lane + 64 * c];
            const int base = (lane + 64 * c) * 8;
            pl[base + 0] = bf2f((unsigned short)(v.x & 0xffffu));
            pl[base + 1] = bf2f((unsigned short)(v.x >> 16));
            pl[base + 2] = bf2f((unsigned short)(v.y & 0xffffu));
            pl[base + 3] = bf2f((unsigned short)(v.y >> 16));
            pl[base + 4] = bf2f((unsigned short)(v.z & 0xffffu));
            pl[base + 5] = bf2f((unsigned short)(v.z >> 16));
            pl[base + 6] = bf2f((unsigned short)(v.w & 0xffffu));
            pl[base + 7] = bf2f((unsigned short)(v.w >> 16));
        }
        // wave-private LDS: compiler inserts lgkmcnt waits; no barrier needed

        // walk root -> depth-6 node (63+lane), bits MSB-first
        float mu = 1.f; int node = 0;
#pragma unroll
        for (int d = 0; d < 6; ++d) {
            const int bit = (lane >> (5 - d)) & 1;
            const float pv = pl[node];
            mu *= bit ? (1.f - pv) : pv;
            node = 2 * node + 1 + bit;
        }
        // expand 16-leaf subtree in registers
        float m1[2], m2[4], m3[8], m4[16];
        {
            const float pv = pl[63 + lane];
            m1[0] = mu * pv; m1[1] = mu * (1.f - pv);
        }
#pragma unroll
        for (int i = 0; i < 2; ++i) {
            const float pv = pl[127 + 2 * lane + i];
            m2[2 * i] = m1[i] * pv; m2[2 * i + 1] = m1[i] * (1.f - pv);
        }
#pragma unroll
        for (int i = 0; i < 4; ++i) {
            const float pv = pl[255 + 4 * lane + i];
            m3[2 * i] = m2[i] * pv; m3[2 * i + 1] = m2[i] * (1.f - pv);
        }
#pragma unroll
        for (int i = 0; i < 8; ++i) {
            const float pv = pl[511 + 8 * lane + i];
            m4[2 * i] = m3[i] * pv; m4[2 * i + 1] = m3[i] * (1.f - pv);
        }
#pragma unroll
        for (int i = 0; i < 16; ++i) lsum[i] += m4[i];

        // y[o] = sum_leaf mu * W_leaf[o][leaf]; lane owns leaves lane*16+i
#pragma unroll
        for (int o = 0; o < OUTD; ++o) {
            float s = 0.f;
#pragma unroll
            for (int i = 0; i < 16; ++i) {
                const int ii = (i + lane) & 15;   // rotate to dodge bank conflicts
                s = fmaf(m4[ii], wl[o * NLEAF + lane * 16 + ii], s);
            }
#pragma unroll
            for (int off = 32; off >= 1; off >>= 1) s += __shfl_xor(s, off, 64);
            yp[o] = s;
        }
        if (lane == 0) {
#pragma unroll
            for (int o = 0; o < OUTD; ++o) Y[(size_t)row * OUTD + o] = yp[o];
        }
    }

    __syncthreads();   // everyone done using buf as p-row staging
#pragma unroll
    for (int i = 0; i < 16; ++i) {
        const int ii = (i + lane) & 15;
        buf[wave][lane * 16 + ii] = lsum[ii];
    }
    __syncthreads();
    for (int idx = tid; idx < NLEAF; idx += 256) {
        const float s = buf[0][idx] + buf[1][idx] + buf[2][idx] + buf[3][idx];
        atomicAdd(&leafsum[idx], s);
    }
}

// ---------------- Pass C: penalty ----------------
__global__ __launch_bounds__(1024)
void sdt_penalty(const float* __restrict__ leafsum, float* __restrict__ pen_out)
{
    __shared__ float t[NLEAF];
    __shared__ float red[1024];
    const int tid = threadIdx.x;
    t[tid] = leafsum[tid];
    __syncthreads();
    float pen = 0.f;
    for (int d = NDEPTH; d >= 1; --d) {
        const int n = 1 << d;
        if (tid < n) {
            const float num = t[tid];
            const float par = t[tid & ~1] + t[tid | 1];
            const float a = num / par;
            const float coeff = LAMDA * exp2f((float)(1 - d));  // lambda * 2^-(layer)
            pen -= 0.5f * coeff * (logf(a) + logf(1.f - a));
        }
        float s = 0.f;
        if (tid < (n >> 1)) s = t[2 * tid] + t[2 * tid + 1];
        __syncthreads();
        if (tid < (n >> 1)) t[tid] = s;
        __syncthreads();
    }
    red[tid] = pen;
    __syncthreads();
    for (int off = 512; off >= 1; off >>= 1) {
        if (tid < off) red[tid] += red[tid + off];
        __syncthreads();
    }
    if (tid == 0) pen_out[0] = red[0];
}

extern "C" void kernel_launch(void* const* d_in, const int* in_sizes, int n_in,
                              void* d_out, int out_size, void* d_ws, size_t ws_size,
                              hipStream_t stream)
{
    const float* X  = (const float*)d_in[0];
    const float* Wi = (const float*)d_in[1];
    const float* Wl = (const float*)d_in[2];
    float* Y   = (float*)d_out;                    // [32768][10]
    float* pen = Y + (size_t)BROWS * OUTD;         // scalar at index 327680

    unsigned short* P = (unsigned short*)d_ws;     // [32768][1024] bf16 = 67.1 MB
    float* leafsum = (float*)((char*)d_ws + (size_t)BROWS * NP * sizeof(unsigned short));

    hipMemsetAsync(leafsum, 0, NLEAF * sizeof(float), stream);

    dim3 gA(NP / BN, BROWS / BM);   // (8, 256)
    sdt_gemm<<<gA, 256, 0, stream>>>(X, Wi, P);
    sdt_tree<<<BROWS / 32, 256, 0, stream>>>(P, Wl, Y, leafsum);
    sdt_penalty<<<1, 1024, 0, stream>>>(leafsum, pen);
}

// Round 2
// 339.717 us; speedup vs baseline: 2.5117x; 2.5117x over previous
//
#include <hip/hip_runtime.h>
#include <stdint.h>

// Soft Decision Tree forward, MI355X (gfx950)
// Pass P: split W_inner -> bf16 hi/lo, padded [1024][800], + bias[1024]
// Pass A: p = sigmoid([1,X] @ W_inner^T) via 3-term bf16-split MFMA -> bf16 P in ws
// Pass B: tree sweep -> y_pred, leaf sums
// Pass C: penalty from leaf sums

#define BROWS 32768
#define KDIM  784
#define KPAD  800
#define NNODE 1023
#define NP    1024
#define NLEAF 1024
#define OUTD  10
#define NDEPTH 10
#define LAMDA 1e-3f

typedef __attribute__((ext_vector_type(8))) short short8;   // 8 bf16 (4 VGPR)
typedef __attribute__((ext_vector_type(4))) float f32x4;    // MFMA C/D

__device__ __forceinline__ unsigned short f2bf(float f) {
    unsigned int u = __float_as_uint(f);
    u = u + 0x7FFFu + ((u >> 16) & 1u);   // RNE
    return (unsigned short)(u >> 16);
}
__device__ __forceinline__ float bf2f(unsigned short h) {
    return __uint_as_float(((unsigned int)h) << 16);
}

// ---------------- Pass P: W split ----------------
__global__ __launch_bounds__(256)
void sdt_wsplit(const float* __restrict__ Wi, unsigned short* __restrict__ Wh,
                unsigned short* __restrict__ Wl, float* __restrict__ bias)
{
    const int row = blockIdx.x;          // 0..1023
    const int tid = threadIdx.x;
    if (row < NNODE) {
        for (int k = tid; k < KPAD; k += 256) {
            const float x = (k < KDIM) ? Wi[(size_t)row * (KDIM + 1) + 1 + k] : 0.f;
            const unsigned short h = f2bf(x);
            const float lo = x - bf2f(h);
            Wh[(size_t)row * KPAD + k] = h;
            Wl[(size_t)row * KPAD + k] = f2bf(lo);
        }
        if (tid == 0) bias[row] = Wi[(size_t)row * (KDIM + 1)];
    } else {
        for (int k = tid; k < KPAD; k += 256) {
            Wh[(size_t)row * KPAD + k] = 0;
            Wl[(size_t)row * KPAD + k] = 0;
        }
        if (tid == 0) bias[row] = 0.f;
    }
}

// ---------------- Pass A: MFMA GEMM + sigmoid ----------------
// 128x128 tile, BK=32, 256 threads = 4 waves (2x2 of 64x64 sub-tiles).
// LDS row stride 40 bf16 (80 B = 5 x 16B superbanks -> conflict-free b128 reads).
#define LDA_S 40
#define TRS   72   // epilogue transpose stride (144 B, 16B-aligned rows)

__device__ __forceinline__ void cvt4(float4 v, unsigned int& h01, unsigned int& h23,
                                     unsigned int& l01, unsigned int& l23)
{
    const unsigned short h0 = f2bf(v.x), h1 = f2bf(v.y), h2 = f2bf(v.z), h3 = f2bf(v.w);
    const float r0 = v.x - bf2f(h0), r1 = v.y - bf2f(h1), r2 = v.z - bf2f(h2), r3 = v.w - bf2f(h3);
    h01 = (unsigned int)h0 | ((unsigned int)h1 << 16);
    h23 = (unsigned int)h2 | ((unsigned int)h3 << 16);
    l01 = (unsigned int)f2bf(r0) | ((unsigned int)f2bf(r1) << 16);
    l23 = (unsigned int)f2bf(r2) | ((unsigned int)f2bf(r3) << 16);
}

__global__ __launch_bounds__(256, 2)
void sdt_gemm_mfma(const float* __restrict__ X, const unsigned short* __restrict__ Wh,
                   const unsigned short* __restrict__ Wl, const float* __restrict__ bias,
                   unsigned short* __restrict__ P)
{
    __shared__ __align__(16) unsigned short lds[20480];   // 40 KB
    unsigned short* sAh = lds;
    unsigned short* sAl = lds + 5120;
    unsigned short* sBh = lds + 10240;
    unsigned short* sBl = lds + 15360;

    const int tid  = threadIdx.x;
    const int wave = tid >> 6, lane = tid & 63;
    const int wr = wave >> 1, wc = wave & 1;      // wave -> 64x64 sub-tile
    const int col0 = blockIdx.x * 128;            // N (nodes)
    const int row0 = blockIdx.y * 128;            // M (batch)

    const int srow = tid >> 1;                    // staging row 0..127
    const int skh  = (tid & 1) << 4;              // staging k-half: 0 | 16

    f32x4 acc[4][4];
#pragma unroll
    for (int i = 0; i < 4; ++i)
#pragma unroll
        for (int j = 0; j < 4; ++j) acc[i][j] = (f32x4)0.f;

    uint4 ah0, ah1, al0, al1;   // staged A hi/lo (16 bf16 each)
    uint4 bh0, bh1, bl0, bl1;   // staged B hi/lo

    // ---- load k-chunk `it` into staging registers ----
#define LOAD_AB(it_)                                                                  \
    {                                                                                 \
        const int k0_ = (it_) * 32 + skh;                                             \
        if (k0_ < KDIM) {                                                             \
            const float4* asrc = reinterpret_cast<const float4*>(                     \
                &X[(size_t)(row0 + srow) * KDIM + k0_]);                              \
            float4 x0 = asrc[0], x1 = asrc[1], x2 = asrc[2], x3 = asrc[3];            \
            cvt4(x0, ah0.x, ah0.y, al0.x, al0.y);                                     \
            cvt4(x1, ah0.z, ah0.w, al0.z, al0.w);                                     \
            cvt4(x2, ah1.x, ah1.y, al1.x, al1.y);                                     \
            cvt4(x3, ah1.z, ah1.w, al1.z, al1.w);                                     \
        } else {                                                                      \
            ah0 = ah1 = al0 = al1 = make_uint4(0, 0, 0, 0);                           \
        }                                                                             \
        const size_t bbase = (size_t)(col0 + srow) * KPAD + (it_) * 32 + skh;         \
        bh0 = *reinterpret_cast<const uint4*>(&Wh[bbase]);                            \
        bh1 = *reinterpret_cast<const uint4*>(&Wh[bbase + 8]);                        \
        bl0 = *reinterpret_cast<const uint4*>(&Wl[bbase]);                            \
        bl1 = *reinterpret_cast<const uint4*>(&Wl[bbase + 8]);                        \
    }

    LOAD_AB(0);

    const int fr = lane & 15;            // fragment row/col
    const int fk = (lane >> 4) * 8;      // fragment k offset

    for (int it = 0; it < 25; ++it) {
        if (it) __syncthreads();
        // stage registers -> LDS
        *reinterpret_cast<uint4*>(&sAh[srow * LDA_S + skh])     = ah0;
        *reinterpret_cast<uint4*>(&sAh[srow * LDA_S + skh + 8]) = ah1;
        *reinterpret_cast<uint4*>(&sAl[srow * LDA_S + skh])     = al0;
        *reinterpret_cast<uint4*>(&sAl[srow * LDA_S + skh + 8]) = al1;
        *reinterpret_cast<uint4*>(&sBh[srow * LDA_S + skh])     = bh0;
        *reinterpret_cast<uint4*>(&sBh[srow * LDA_S + skh + 8]) = bh1;
        *reinterpret_cast<uint4*>(&sBl[srow * LDA_S + skh])     = bl0;
        *reinterpret_cast<uint4*>(&sBl[srow * LDA_S + skh + 8]) = bl1;
        __syncthreads();

        if (it < 24) LOAD_AB(it + 1);    // prefetch next chunk (overlaps MFMA)

        short8 a_h[4], a_l[4], b_h[4], b_l[4];
#pragma unroll
        for (int i = 0; i < 4; ++i) {
            a_h[i] = *reinterpret_cast<const short8*>(&sAh[(wr * 64 + i * 16 + fr) * LDA_S + fk]);
            a_l[i] = *reinterpret_cast<const short8*>(&sAl[(wr * 64 + i * 16 + fr) * LDA_S + fk]);
            b_h[i] = *reinterpret_cast<const short8*>(&sBh[(wc * 64 + i * 16 + fr) * LDA_S + fk]);
            b_l[i] = *reinterpret_cast<const short8*>(&sBl[(wc * 64 + i * 16 + fr) * LDA_S + fk]);
        }
#pragma unroll
        for (int am = 0; am < 4; ++am)
#pragma unroll
            for (int bn = 0; bn < 4; ++bn) {
                acc[am][bn] = __builtin_amdgcn_mfma_f32_16x16x32_bf16(a_h[am], b_h[bn], acc[am][bn], 0, 0, 0);
                acc[am][bn] = __builtin_amdgcn_mfma_f32_16x16x32_bf16(a_h[am], b_l[bn], acc[am][bn], 0, 0, 0);
                acc[am][bn] = __builtin_amdgcn_mfma_f32_16x16x32_bf16(a_l[am], b_h[bn], acc[am][bn], 0, 0, 0);
            }
    }

    // ---- epilogue: bias + sigmoid, LDS transpose, coalesced bf16 stores ----
    __syncthreads();                       // done with staging buffers
    unsigned short* tr = lds + wave * (64 * TRS);
    const int q = lane >> 4;

    float bias_v[4];
#pragma unroll
    for (int bn = 0; bn < 4; ++bn)
        bias_v[bn] = bias[col0 + wc * 64 + bn * 16 + fr];

#pragma unroll
    for (int am = 0; am < 4; ++am)
#pragma unroll
        for (int reg = 0; reg < 4; ++reg) {
            const int rl = am * 16 + q * 4 + reg;
#pragma unroll
            for (int bn = 0; bn < 4; ++bn) {
                const float z = acc[am][bn][reg] + bias_v[bn];
                const float p = 1.f / (1.f + __expf(-z));
                tr[rl * TRS + bn * 16 + fr] = f2bf(p);
            }
        }
    __syncthreads();                       // make per-wave LDS writes visible

#pragma unroll
    for (int i = 0; i < 8; ++i) {
        const int rl = i * 8 + (lane >> 3);
        const uint4 v = *reinterpret_cast<const uint4*>(&tr[rl * TRS + (lane & 7) * 8]);
        *reinterpret_cast<uint4*>(
            &P[(size_t)(row0 + wr * 64 + rl) * NP + col0 + wc * 64 + (lane & 7) * 8]) = v;
    }
}

// ---------------- Pass B: tree sweep + leaf GEMV + leaf sums ----------------
__global__ __launch_bounds__(256)
void sdt_tree(const unsigned short* __restrict__ P, const float* __restrict__ Wl,
              float* __restrict__ Y, float* __restrict__ leafsum)
{
    __shared__ float wl[OUTD * NLEAF];  // 40 KB
    __shared__ float buf[4][NP];        // 16 KB
    const int tid = threadIdx.x;
    const int wave = tid >> 6, lane = tid & 63;

    for (int idx = tid; idx < (OUTD * NLEAF) / 4; idx += 256)
        reinterpret_cast<float4*>(wl)[idx] = reinterpret_cast<const float4*>(Wl)[idx];
    __syncthreads();

    float lsum[16];
#pragma unroll
    for (int i = 0; i < 16; ++i) lsum[i] = 0.f;

    float* pl = buf[wave];
    const int rowbase = blockIdx.x * 32 + wave * 8;
    float yp[OUTD];

    for (int r = 0; r < 8; ++r) {
        const int row = rowbase + r;
        const uint4* prow = reinterpret_cast<const uint4*>(P + (size_t)row * NP);
#pragma unroll
        for (int c = 0; c < 2; ++c) {
            const uint4 v = prow[lane + 64 * c];
            const int base = (lane + 64 * c) * 8;
            pl[base + 0] = bf2f((unsigned short)(v.x & 0xffffu));
            pl[base + 1] = bf2f((unsigned short)(v.x >> 16));
            pl[base + 2] = bf2f((unsigned short)(v.y & 0xffffu));
            pl[base + 3] = bf2f((unsigned short)(v.y >> 16));
            pl[base + 4] = bf2f((unsigned short)(v.z & 0xffffu));
            pl[base + 5] = bf2f((unsigned short)(v.z >> 16));
            pl[base + 6] = bf2f((unsigned short)(v.w & 0xffffu));
            pl[base + 7] = bf2f((unsigned short)(v.w >> 16));
        }

        float mu = 1.f; int node = 0;
#pragma unroll
        for (int d = 0; d < 6; ++d) {
            const int bit = (lane >> (5 - d)) & 1;
            const float pv = pl[node];
            mu *= bit ? (1.f - pv) : pv;
            node = 2 * node + 1 + bit;
        }
        float m1[2], m2[4], m3[8], m4[16];
        {
            const float pv = pl[63 + lane];
            m1[0] = mu * pv; m1[1] = mu * (1.f - pv);
        }
#pragma unroll
        for (int i = 0; i < 2; ++i) {
            const float pv = pl[127 + 2 * lane + i];
            m2[2 * i] = m1[i] * pv; m2[2 * i + 1] = m1[i] * (1.f - pv);
        }
#pragma unroll
        for (int i = 0; i < 4; ++i) {
            const float pv = pl[255 + 4 * lane + i];
            m3[2 * i] = m2[i] * pv; m3[2 * i + 1] = m2[i] * (1.f - pv);
        }
#pragma unroll
        for (int i = 0; i < 8; ++i) {
            const float pv = pl[511 + 8 * lane + i];
            m4[2 * i] = m3[i] * pv; m4[2 * i + 1] = m3[i] * (1.f - pv);
        }
#pragma unroll
        for (int i = 0; i < 16; ++i) lsum[i] += m4[i];

#pragma unroll
        for (int o = 0; o < OUTD; ++o) {
            float s = 0.f;
#pragma unroll
            for (int i = 0; i < 16; ++i) {
                const int ii = (i + lane) & 15;
                s = fmaf(m4[ii], wl[o * NLEAF + lane * 16 + ii], s);
            }
#pragma unroll
            for (int off = 32; off >= 1; off >>= 1) s += __shfl_xor(s, off, 64);
            yp[o] = s;
        }
        if (lane == 0) {
#pragma unroll
            for (int o = 0; o < OUTD; ++o) Y[(size_t)row * OUTD + o] = yp[o];
        }
    }

    __syncthreads();
#pragma unroll
    for (int i = 0; i < 16; ++i) {
        const int ii = (i + lane) & 15;
        buf[wave][lane * 16 + ii] = lsum[ii];
    }
    __syncthreads();
    for (int idx = tid; idx < NLEAF; idx += 256) {
        const float s = buf[0][idx] + buf[1][idx] + buf[2][idx] + buf[3][idx];
        atomicAdd(&leafsum[idx], s);
    }
}

// ---------------- Pass C: penalty ----------------
__global__ __launch_bounds__(1024)
void sdt_penalty(const float* __restrict__ leafsum, float* __restrict__ pen_out)
{
    __shared__ float t[NLEAF];
    __shared__ float red[1024];
    const int tid = threadIdx.x;
    t[tid] = leafsum[tid];
    __syncthreads();
    float pen = 0.f;
    for (int d = NDEPTH; d >= 1; --d) {
        const int n = 1 << d;
        if (tid < n) {
            const float num = t[tid];
            const float par = t[tid & ~1] + t[tid | 1];
            const float a = num / par;
            const float coeff = LAMDA * exp2f((float)(1 - d));
            pen -= 0.5f * coeff * (logf(a) + logf(1.f - a));
        }
        float s = 0.f;
        if (tid < (n >> 1)) s = t[2 * tid] + t[2 * tid + 1];
        __syncthreads();
        if (tid < (n >> 1)) t[tid] = s;
        __syncthreads();
    }
    red[tid] = pen;
    __syncthreads();
    for (int off = 512; off >= 1; off >>= 1) {
        if (tid < off) red[tid] += red[tid + off];
        __syncthreads();
    }
    if (tid == 0) pen_out[0] = red[0];
}

extern "C" void kernel_launch(void* const* d_in, const int* in_sizes, int n_in,
                              void* d_out, int out_size, void* d_ws, size_t ws_size,
                              hipStream_t stream)
{
    const float* X  = (const float*)d_in[0];
    const float* Wi = (const float*)d_in[1];
    const float* Wl = (const float*)d_in[2];
    float* Y   = (float*)d_out;                    // [32768][10]
    float* pen = Y + (size_t)BROWS * OUTD;

    char* ws = (char*)d_ws;
    unsigned short* P  = (unsigned short*)ws;                          // 67,108,864 B
    unsigned short* Wh = (unsigned short*)(ws + 67108864);             // 1,638,400 B
    unsigned short* Wls = (unsigned short*)(ws + 67108864 + 1638400);  // 1,638,400 B
    float* bias    = (float*)(ws + 67108864 + 2 * 1638400);            // 4096 B
    float* leafsum = (float*)(ws + 67108864 + 2 * 1638400 + 4096);     // 4096 B

    hipMemsetAsync(leafsum, 0, NLEAF * sizeof(float), stream);

    sdt_wsplit<<<1024, 256, 0, stream>>>(Wi, Wh, Wls, bias);
    dim3 gA(NP / 128, BROWS / 128);   // (8, 256)
    sdt_gemm_mfma<<<gA, 256, 0, stream>>>(X, Wh, Wls, bias, P);
    sdt_tree<<<BROWS / 32, 256, 0, stream>>>(P, Wl, Y, leafsum);
    sdt_penalty<<<1, 1024, 0, stream>>>(leafsum, pen);
}

// Round 3
// 271.376 us; speedup vs baseline: 3.1442x; 1.2518x over previous
//
#include <hip/hip_runtime.h>
#include <stdint.h>

// Soft Decision Tree forward, MI355X (gfx950)
// Main path (needs ~177MB ws):
//   xsplit: X -> Xs = [hi|lo] bf16 [32768][1600]
//   wsplit: W_inner -> Ws = [hi|hi|lo|0] bf16 [1024][2432], bias[1024]
//   gemm8 : P = sigmoid(bias + Xs' @ Ws^T) via 256x256 8-phase MFMA (K'=2432,
//           A-section2 aliased to section0 through per-lane global_load_lds addrs)
//   tree  : path-prob sweep -> y_pred + leaf sums
//   penalty: tree reduction of leaf sums
// Fallback path (ws < 177MB): round-2 validated 128^2 3-term MFMA GEMM.

#define BROWS 32768
#define KDIM  784
#define NNODE 1023
#define NP    1024
#define NLEAF 1024
#define OUTD  10
#define NDEPTH 10
#define LAMDA 1e-3f

#define GKS   1600          // Xs row stride (hi 800 | lo 800)
#define GKW   2432          // Ws row stride (hi 800 | hi 800 | lo 800 | 32 zeros)
#define NT    38            // K' tiles of 64

typedef __attribute__((ext_vector_type(8))) short short8;
typedef __attribute__((ext_vector_type(4))) float f32x4;

__device__ __forceinline__ unsigned short f2bf(float f) {
    unsigned int u = __float_as_uint(f);
    u = u + 0x7FFFu + ((u >> 16) & 1u);   // RNE
    return (unsigned short)(u >> 16);
}
__device__ __forceinline__ float bf2f(unsigned short h) {
    return __uint_as_float(((unsigned int)h) << 16);
}

// ============================ Pass X: X split =============================
__global__ __launch_bounds__(256)
void sdt_xsplit(const float* __restrict__ X, unsigned short* __restrict__ Xs)
{
    const int g   = blockIdx.x * 256 + threadIdx.x;   // [0, 32768*100)
    const int row = g / 100, grp = g % 100;
    unsigned int hi[4], lo[4];
    if (grp < 98) {
        const float4* src = reinterpret_cast<const float4*>(&X[(size_t)row * KDIM + grp * 8]);
        const float4 v0 = src[0], v1 = src[1];
        const float v[8] = {v0.x, v0.y, v0.z, v0.w, v1.x, v1.y, v1.z, v1.w};
#pragma unroll
        for (int i = 0; i < 4; ++i) {
            const unsigned short h0 = f2bf(v[2*i]), h1 = f2bf(v[2*i+1]);
            const unsigned short l0 = f2bf(v[2*i] - bf2f(h0));
            const unsigned short l1 = f2bf(v[2*i+1] - bf2f(h1));
            hi[i] = (unsigned int)h0 | ((unsigned int)h1 << 16);
            lo[i] = (unsigned int)l0 | ((unsigned int)l1 << 16);
        }
    } else {
#pragma unroll
        for (int i = 0; i < 4; ++i) { hi[i] = 0u; lo[i] = 0u; }
    }
    *reinterpret_cast<uint4*>(&Xs[(size_t)row * GKS + grp * 8])       = make_uint4(hi[0], hi[1], hi[2], hi[3]);
    *reinterpret_cast<uint4*>(&Xs[(size_t)row * GKS + 800 + grp * 8]) = make_uint4(lo[0], lo[1], lo[2], lo[3]);
}

// ============================ Pass W: W split =============================
__global__ __launch_bounds__(256)
void sdt_wsplit(const float* __restrict__ Wi, unsigned short* __restrict__ Ws,
                float* __restrict__ bias)
{
    const int row = blockIdx.x;          // 0..1023
    const int tid = threadIdx.x;
    for (int c = tid; c < GKW; c += 256) {
        unsigned short v = 0;
        if (row < NNODE) {
            if (c < 1600) {                       // two hi sections
                const int k = (c < 800) ? c : c - 800;
                if (k < KDIM) v = f2bf(Wi[(size_t)row * (KDIM + 1) + 1 + k]);
            } else if (c < 2400) {                // lo section
                const int k = c - 1600;
                if (k < KDIM) {
                    const float x = Wi[(size_t)row * (KDIM + 1) + 1 + k];
                    v = f2bf(x - bf2f(f2bf(x)));
                }
            }
        }
        Ws[(size_t)row * GKW + c] = v;
    }
    if (tid == 0) bias[row] = (row < NNODE) ? Wi[(size_t)row * (KDIM + 1)] : 0.f;
}

// ===================== Pass A (main): 256x256 8-phase MFMA GEMM =====================
#define BAR() { __builtin_amdgcn_sched_barrier(0); __builtin_amdgcn_s_barrier(); __builtin_amdgcn_sched_barrier(0); }

#define STAGE(ktn, osel)                                                              \
    {                                                                                 \
        const int kt_ = (ktn);                                                        \
        const int kA_ = (kt_ < 25) ? kt_ * 64 : kt_ * 64 - 1600;                      \
        const int kB_ = kt_ * 64;                                                     \
        unsigned short* ab_ = lds + (osel) * 32768;                                   \
        unsigned short* bb_ = ab_ + 16384;                                            \
        _Pragma("unroll")                                                             \
        for (int j = 0; j < 4; ++j)                                                   \
            __builtin_amdgcn_global_load_lds(                                         \
                (const __attribute__((address_space(1))) void*)(pA[j] + kA_),         \
                (__attribute__((address_space(3))) void*)(ab_ + (j * 512 + wave * 64) * 8), \
                16, 0, 0);                                                            \
        _Pragma("unroll")                                                             \
        for (int j = 0; j < 4; ++j)                                                   \
            __builtin_amdgcn_global_load_lds(                                         \
                (const __attribute__((address_space(1))) void*)(pB[j] + kB_),         \
                (__attribute__((address_space(3))) void*)(bb_ + (j * 512 + wave * 64) * 8), \
                16, 0, 0);                                                            \
    }

#define LDA4(dst, mb, kk, ab_)                                                        \
    _Pragma("unroll")                                                                 \
    for (int mi = 0; mi < 4; ++mi) {                                                  \
        const int row_ = wr * 128 + ((mb) + mi) * 16 + fr;                            \
        dst[mi] = *reinterpret_cast<const short8*>(                                   \
            (ab_) + row_ * 64 + ((((kk) * 4 + q4) ^ sw) * 8));                        \
    }

#define LDB4(dst, kk, bb_)                                                            \
    _Pragma("unroll")                                                                 \
    for (int n = 0; n < 4; ++n) {                                                     \
        const int row_ = wc * 64 + n * 16 + fr;                                       \
        dst[n] = *reinterpret_cast<const short8*>(                                    \
            (bb_) + row_ * 64 + ((((kk) * 4 + q4) ^ sw) * 8));                        \
    }

#define MFMA16(mb, av, bv)                                                            \
    _Pragma("unroll")                                                                 \
    for (int mi = 0; mi < 4; ++mi)                                                    \
        _Pragma("unroll")                                                             \
        for (int n = 0; n < 4; ++n)                                                   \
            acc[(mb) + mi][n] = __builtin_amdgcn_mfma_f32_16x16x32_bf16(              \
                av[mi], bv[n], acc[(mb) + mi][n], 0, 0, 0);

__global__ __launch_bounds__(512, 2)
void sdt_gemm8(const unsigned short* __restrict__ Xs, const unsigned short* __restrict__ Ws,
               const float* __restrict__ bias, unsigned short* __restrict__ P)
{
    __shared__ __align__(16) unsigned short lds[65536];   // 128 KB

    const int tid  = threadIdx.x;
    const int wave = tid >> 6, lane = tid & 63;
    const int wr = wave >> 2, wc = wave & 3;              // 2x4 wave grid -> 128x64 per wave
    // XCD-aware swizzle: 512 blocks, 64 contiguous per XCD
    const int b  = blockIdx.x;
    const int wg = (b & 7) * 64 + (b >> 3);
    const int col0 = (wg & 3) * 256;
    const int row0 = (wg >> 2) * 256;

    const int fr = lane & 15;
    const int q4 = lane >> 4;
    const int sw = lane & 7;

    f32x4 acc[8][4];
#pragma unroll
    for (int i = 0; i < 8; ++i)
#pragma unroll
        for (int j = 0; j < 4; ++j) acc[i][j] = (f32x4)0.f;

    // staging sources: chunk c = j*512 + tid; LDS linear chunk c holds logical
    // (row = c>>3, kc = (c&7)^(row&7)); global addr pre-inverse-swizzled.
    const unsigned short* pA[4];
    const unsigned short* pB[4];
#pragma unroll
    for (int j = 0; j < 4; ++j) {
        const int c = j * 512 + tid;
        const int r = c >> 3;
        const int kcl = (c & 7) ^ (r & 7);
        pA[j] = Xs + (size_t)(row0 + r) * GKS + kcl * 8;
        pB[j] = Ws + (size_t)(col0 + r) * GKW + kcl * 8;
    }

    STAGE(0, 0);
    asm volatile("s_waitcnt vmcnt(0)" ::: "memory");
    BAR();

#pragma unroll 1
    for (int kt = 0; kt < NT; ++kt) {
        const int cur = kt & 1;
        const unsigned short* ab = lds + cur * 32768;
        const unsigned short* bb = ab + 16384;
        short8 a[4], bfr[4];

        // ---- phase 0: m0-3, kk0 ----
        LDA4(a, 0, 0, ab);
        LDB4(bfr, 0, bb);
        if (kt + 1 < NT) STAGE(kt + 1, cur ^ 1);
        BAR();
        __builtin_amdgcn_s_setprio(1);
        MFMA16(0, a, bfr);
        __builtin_amdgcn_s_setprio(0);
        BAR();
        // ---- phase 1: m4-7, kk0 ----
        LDA4(a, 4, 0, ab);
        BAR();
        __builtin_amdgcn_s_setprio(1);
        MFMA16(4, a, bfr);
        __builtin_amdgcn_s_setprio(0);
        BAR();
        // ---- phase 2: m0-3, kk1 ----
        LDA4(a, 0, 1, ab);
        LDB4(bfr, 1, bb);
        BAR();
        __builtin_amdgcn_s_setprio(1);
        MFMA16(0, a, bfr);
        __builtin_amdgcn_s_setprio(0);
        BAR();
        // ---- phase 3: m4-7, kk1 ----
        LDA4(a, 4, 1, ab);
        BAR();
        __builtin_amdgcn_s_setprio(1);
        MFMA16(4, a, bfr);
        __builtin_amdgcn_s_setprio(0);
        // counted-drain: next tile's 8 stages were issued 3 phases ago (>HBM latency)
        asm volatile("s_waitcnt vmcnt(0)" ::: "memory");
        BAR();
    }

    // ---- epilogue: bias + sigmoid, per-wave LDS transpose, coalesced stores ----
    __syncthreads();
    unsigned short* tr = lds + wave * 8192;   // 16 KB per wave (128 rows x 64 cols bf16)
    float bv[4];
#pragma unroll
    for (int n = 0; n < 4; ++n) bv[n] = bias[col0 + wc * 64 + n * 16 + fr];

#pragma unroll
    for (int m = 0; m < 8; ++m)
#pragma unroll
        for (int reg = 0; reg < 4; ++reg) {
            const int rl = m * 16 + q4 * 4 + reg;
#pragma unroll
            for (int n = 0; n < 4; ++n) {
                const float z = acc[m][n][reg] + bv[n];
                const float p = 1.f / (1.f + __expf(-z));
                tr[rl * 64 + n * 16 + fr] = f2bf(p);
            }
        }
    // wave-private readback (no barrier needed)
#pragma unroll
    for (int it = 0; it < 16; ++it) {
        const int r  = it * 8 + (lane >> 3);
        const int c8 = (lane & 7) * 8;
        const uint4 v = *reinterpret_cast<const uint4*>(tr + r * 64 + c8);
        *reinterpret_cast<uint4*>(
            &P[(size_t)(row0 + wr * 128 + r) * NP + col0 + wc * 64 + c8]) = v;
    }
}

// ===================== Fallback pass A: round-2 validated 128^2 GEMM =====================
#define LDA_S 40
#define TRS   72

__global__ __launch_bounds__(256)
void sdt_wsplit2(const float* __restrict__ Wi, unsigned short* __restrict__ Wh,
                 unsigned short* __restrict__ Wl, float* __restrict__ bias)
{
    const int row = blockIdx.x;
    const int tid = threadIdx.x;
    if (row < NNODE) {
        for (int k = tid; k < 800; k += 256) {
            const float x = (k < KDIM) ? Wi[(size_t)row * (KDIM + 1) + 1 + k] : 0.f;
            const unsigned short h = f2bf(x);
            Wh[(size_t)row * 800 + k] = h;
            Wl[(size_t)row * 800 + k] = f2bf(x - bf2f(h));
        }
        if (tid == 0) bias[row] = Wi[(size_t)row * (KDIM + 1)];
    } else {
        for (int k = tid; k < 800; k += 256) {
            Wh[(size_t)row * 800 + k] = 0;
            Wl[(size_t)row * 800 + k] = 0;
        }
        if (tid == 0) bias[row] = 0.f;
    }
}

__device__ __forceinline__ void cvt4(float4 v, unsigned int& h01, unsigned int& h23,
                                     unsigned int& l01, unsigned int& l23)
{
    const unsigned short h0 = f2bf(v.x), h1 = f2bf(v.y), h2 = f2bf(v.z), h3 = f2bf(v.w);
    const float r0 = v.x - bf2f(h0), r1 = v.y - bf2f(h1), r2 = v.z - bf2f(h2), r3 = v.w - bf2f(h3);
    h01 = (unsigned int)h0 | ((unsigned int)h1 << 16);
    h23 = (unsigned int)h2 | ((unsigned int)h3 << 16);
    l01 = (unsigned int)f2bf(r0) | ((unsigned int)f2bf(r1) << 16);
    l23 = (unsigned int)f2bf(r2) | ((unsigned int)f2bf(r3) << 16);
}

__global__ __launch_bounds__(256, 2)
void sdt_gemm_mfma(const float* __restrict__ X, const unsigned short* __restrict__ Wh,
                   const unsigned short* __restrict__ Wl, const float* __restrict__ bias,
                   unsigned short* __restrict__ P)
{
    __shared__ __align__(16) unsigned short lds2[20480];
    unsigned short* sAh = lds2;
    unsigned short* sAl = lds2 + 5120;
    unsigned short* sBh = lds2 + 10240;
    unsigned short* sBl = lds2 + 15360;

    const int tid  = threadIdx.x;
    const int wave = tid >> 6, lane = tid & 63;
    const int wr = wave >> 1, wc = wave & 1;
    const int col0 = blockIdx.x * 128;
    const int row0 = blockIdx.y * 128;
    const int srow = tid >> 1;
    const int skh  = (tid & 1) << 4;

    f32x4 acc[4][4];
#pragma unroll
    for (int i = 0; i < 4; ++i)
#pragma unroll
        for (int j = 0; j < 4; ++j) acc[i][j] = (f32x4)0.f;

    uint4 ah0, ah1, al0, al1, bh0, bh1, bl0, bl1;

#define LOAD_AB2(it_)                                                                 \
    {                                                                                 \
        const int k0_ = (it_) * 32 + skh;                                             \
        if (k0_ < KDIM) {                                                             \
            const float4* asrc = reinterpret_cast<const float4*>(                     \
                &X[(size_t)(row0 + srow) * KDIM + k0_]);                              \
            float4 x0 = asrc[0], x1 = asrc[1], x2 = asrc[2], x3 = asrc[3];            \
            cvt4(x0, ah0.x, ah0.y, al0.x, al0.y);                                     \
            cvt4(x1, ah0.z, ah0.w, al0.z, al0.w);                                     \
            cvt4(x2, ah1.x, ah1.y, al1.x, al1.y);                                     \
            cvt4(x3, ah1.z, ah1.w, al1.z, al1.w);                                     \
        } else {                                                                      \
            ah0 = ah1 = al0 = al1 = make_uint4(0, 0, 0, 0);                           \
        }                                                                             \
        const size_t bbase = (size_t)(col0 + srow) * 800 + (it_) * 32 + skh;          \
        bh0 = *reinterpret_cast<const uint4*>(&Wh[bbase]);                            \
        bh1 = *reinterpret_cast<const uint4*>(&Wh[bbase + 8]);                        \
        bl0 = *reinterpret_cast<const uint4*>(&Wl[bbase]);                            \
        bl1 = *reinterpret_cast<const uint4*>(&Wl[bbase + 8]);                        \
    }

    LOAD_AB2(0);
    const int fr = lane & 15;
    const int fk = (lane >> 4) * 8;

    for (int it = 0; it < 25; ++it) {
        if (it) __syncthreads();
        *reinterpret_cast<uint4*>(&sAh[srow * LDA_S + skh])     = ah0;
        *reinterpret_cast<uint4*>(&sAh[srow * LDA_S + skh + 8]) = ah1;
        *reinterpret_cast<uint4*>(&sAl[srow * LDA_S + skh])     = al0;
        *reinterpret_cast<uint4*>(&sAl[srow * LDA_S + skh + 8]) = al1;
        *reinterpret_cast<uint4*>(&sBh[srow * LDA_S + skh])     = bh0;
        *reinterpret_cast<uint4*>(&sBh[srow * LDA_S + skh + 8]) = bh1;
        *reinterpret_cast<uint4*>(&sBl[srow * LDA_S + skh])     = bl0;
        *reinterpret_cast<uint4*>(&sBl[srow * LDA_S + skh + 8]) = bl1;
        __syncthreads();
        if (it < 24) LOAD_AB2(it + 1);

        short8 a_h[4], a_l[4], b_h[4], b_l[4];
#pragma unroll
        for (int i = 0; i < 4; ++i) {
            a_h[i] = *reinterpret_cast<const short8*>(&sAh[(wr * 64 + i * 16 + fr) * LDA_S + fk]);
            a_l[i] = *reinterpret_cast<const short8*>(&sAl[(wr * 64 + i * 16 + fr) * LDA_S + fk]);
            b_h[i] = *reinterpret_cast<const short8*>(&sBh[(wc * 64 + i * 16 + fr) * LDA_S + fk]);
            b_l[i] = *reinterpret_cast<const short8*>(&sBl[(wc * 64 + i * 16 + fr) * LDA_S + fk]);
        }
#pragma unroll
        for (int am = 0; am < 4; ++am)
#pragma unroll
            for (int bn = 0; bn < 4; ++bn) {
                acc[am][bn] = __builtin_amdgcn_mfma_f32_16x16x32_bf16(a_h[am], b_h[bn], acc[am][bn], 0, 0, 0);
                acc[am][bn] = __builtin_amdgcn_mfma_f32_16x16x32_bf16(a_h[am], b_l[bn], acc[am][bn], 0, 0, 0);
                acc[am][bn] = __builtin_amdgcn_mfma_f32_16x16x32_bf16(a_l[am], b_h[bn], acc[am][bn], 0, 0, 0);
            }
    }

    __syncthreads();
    unsigned short* tr = lds2 + wave * (64 * TRS);
    const int q = lane >> 4;
    float bias_v[4];
#pragma unroll
    for (int bn = 0; bn < 4; ++bn)
        bias_v[bn] = bias[col0 + wc * 64 + bn * 16 + fr];
#pragma unroll
    for (int am = 0; am < 4; ++am)
#pragma unroll
        for (int reg = 0; reg < 4; ++reg) {
            const int rl = am * 16 + q * 4 + reg;
#pragma unroll
            for (int bn = 0; bn < 4; ++bn) {
                const float z = acc[am][bn][reg] + bias_v[bn];
                const float p = 1.f / (1.f + __expf(-z));
                tr[rl * TRS + bn * 16 + fr] = f2bf(p);
            }
        }
    __syncthreads();
#pragma unroll
    for (int i = 0; i < 8; ++i) {
        const int rl = i * 8 + (lane >> 3);
        const uint4 v = *reinterpret_cast<const uint4*>(&tr[rl * TRS + (lane & 7) * 8]);
        *reinterpret_cast<uint4*>(
            &P[(size_t)(row0 + wr * 64 + rl) * NP + col0 + wc * 64 + (lane & 7) * 8]) = v;
    }
}

// ===================== Pass B: tree sweep + leaf GEMV + leaf sums =====================
__global__ __launch_bounds__(256)
void sdt_tree(const unsigned short* __restrict__ P, const float* __restrict__ Wl,
              float* __restrict__ Y, float* __restrict__ leafsum)
{
    __shared__ float wl[OUTD * NLEAF];   // 40 KB
    __shared__ float buf[4][NP];         // 16 KB (p row / leaf-sum scratch)
    __shared__ float red[4][832];        // 13 KB (y reduction, stride 13)
    const int tid = threadIdx.x;
    const int wave = tid >> 6, lane = tid & 63;

    for (int idx = tid; idx < (OUTD * NLEAF) / 4; idx += 256)
        reinterpret_cast<float4*>(wl)[idx] = reinterpret_cast<const float4*>(Wl)[idx];
    __syncthreads();

    float lsum[16];
#pragma unroll
    for (int i = 0; i < 16; ++i) lsum[i] = 0.f;

    float* pl = buf[wave];
    float* rd = red[wave];
    const int rowbase = blockIdx.x * 32 + wave * 8;
    const int o_r   = lane % 10;            // reduction role (lanes < 40)
    const int seg16 = (lane / 10) * 16;

    for (int r = 0; r < 8; ++r) {
        const int row = rowbase + r;
        const uint4* prow = reinterpret_cast<const uint4*>(P + (size_t)row * NP);
#pragma unroll
        for (int c = 0; c < 2; ++c) {
            const uint4 v = prow[lane + 64 * c];
            const int base = (lane + 64 * c) * 8;
            pl[base + 0] = bf2f((unsigned short)(v.x & 0xffffu));
            pl[base + 1] = bf2f((unsigned short)(v.x >> 16));
            pl[base + 2] = bf2f((unsigned short)(v.y & 0xffffu));
            pl[base + 3] = bf2f((unsigned short)(v.y >> 16));
            pl[base + 4] = bf2f((unsigned short)(v.z & 0xffffu));
            pl[base + 5] = bf2f((unsigned short)(v.z >> 16));
            pl[base + 6] = bf2f((unsigned short)(v.w & 0xffffu));
            pl[base + 7] = bf2f((unsigned short)(v.w >> 16));
        }

        // tree walk: root -> depth-6 node (63+lane)
        float mu = 1.f; int node = 0;
#pragma unroll
        for (int d = 0; d < 6; ++d) {
            const int bit = (lane >> (5 - d)) & 1;
            const float pv = pl[node];
            mu *= bit ? (1.f - pv) : pv;
            node = 2 * node + 1 + bit;
        }
        float m1[2], m2[4], m3[8], m4[16];
        {
            const float pv = pl[63 + lane];
            m1[0] = mu * pv; m1[1] = mu * (1.f - pv);
        }
#pragma unroll
        for (int i = 0; i < 2; ++i) {
            const float pv = pl[127 + 2 * lane + i];
            m2[2 * i] = m1[i] * pv; m2[2 * i + 1] = m1[i] * (1.f - pv);
        }
#pragma unroll
        for (int i = 0; i < 4; ++i) {
            const float pv = pl[255 + 4 * lane + i];
            m3[2 * i] = m2[i] * pv; m3[2 * i + 1] = m2[i] * (1.f - pv);
        }
#pragma unroll
        for (int i = 0; i < 8; ++i) {
            const float pv = pl[511 + 8 * lane + i];
            m4[2 * i] = m3[i] * pv; m4[2 * i + 1] = m3[i] * (1.f - pv);
        }
#pragma unroll
        for (int i = 0; i < 16; ++i) lsum[i] += m4[i];

        // y partials: lane owns leaves lane*16..+15, float4 wl reads
#pragma unroll
        for (int o = 0; o < OUTD; ++o) {
            float s = 0.f;
#pragma unroll
            for (int i4 = 0; i4 < 4; ++i4) {
                const float4 w4 = *reinterpret_cast<const float4*>(&wl[o * NLEAF + lane * 16 + i4 * 4]);
                s = fmaf(m4[4 * i4 + 0], w4.x, s);
                s = fmaf(m4[4 * i4 + 1], w4.y, s);
                s = fmaf(m4[4 * i4 + 2], w4.z, s);
                s = fmaf(m4[4 * i4 + 3], w4.w, s);
            }
            rd[lane * 13 + o] = s;
        }
        // reduce 64 partials per output via LDS transpose + 2 shuffles
        float s = 0.f;
        if (lane < 40) {
#pragma unroll
            for (int m = 0; m < 16; ++m) s += rd[(seg16 + m) * 13 + o_r];
        }
        s += __shfl_down(s, 20, 64);
        s += __shfl_down(s, 10, 64);
        if (lane < 10) Y[(size_t)row * OUTD + lane] = s;
    }

    __syncthreads();
#pragma unroll
    for (int i = 0; i < 16; ++i) {
        const int ii = (i + lane) & 15;
        buf[wave][lane * 16 + ii] = lsum[ii];
    }
    __syncthreads();
    for (int idx = tid; idx < NLEAF; idx += 256) {
        const float s = buf[0][idx] + buf[1][idx] + buf[2][idx] + buf[3][idx];
        atomicAdd(&leafsum[idx], s);
    }
}

// ============================ Pass C: penalty ============================
__global__ __launch_bounds__(1024)
void sdt_penalty(const float* __restrict__ leafsum, float* __restrict__ pen_out)
{
    __shared__ float t[NLEAF];
    __shared__ float red1[1024];
    const int tid = threadIdx.x;
    t[tid] = leafsum[tid];
    __syncthreads();
    float pen = 0.f;
    for (int d = NDEPTH; d >= 1; --d) {
        const int n = 1 << d;
        if (tid < n) {
            const float num = t[tid];
            const float par = t[tid & ~1] + t[tid | 1];
            const float a = num / par;
            const float coeff = LAMDA * exp2f((float)(1 - d));
            pen -= 0.5f * coeff * (logf(a) + logf(1.f - a));
        }
        float s = 0.f;
        if (tid < (n >> 1)) s = t[2 * tid] + t[2 * tid + 1];
        __syncthreads();
        if (tid < (n >> 1)) t[tid] = s;
        __syncthreads();
    }
    red1[tid] = pen;
    __syncthreads();
    for (int off = 512; off >= 1; off >>= 1) {
        if (tid < off) red1[tid] += red1[tid + off];
        __syncthreads();
    }
    if (tid == 0) pen_out[0] = red1[0];
}

// ================================ launch ================================
extern "C" void kernel_launch(void* const* d_in, const int* in_sizes, int n_in,
                              void* d_out, int out_size, void* d_ws, size_t ws_size,
                              hipStream_t stream)
{
    const float* X  = (const float*)d_in[0];
    const float* Wi = (const float*)d_in[1];
    const float* Wl = (const float*)d_in[2];
    float* Y   = (float*)d_out;
    float* pen = Y + (size_t)BROWS * OUTD;

    char* ws = (char*)d_ws;
    const size_t P_BYTES  = (size_t)BROWS * NP * 2;            // 67,108,864
    const size_t XS_BYTES = (size_t)BROWS * GKS * 2;           // 104,857,600
    const size_t WS_BYTES = (size_t)NP * GKW * 2;              // 4,980,736
    const size_t NEED_MAIN = P_BYTES + XS_BYTES + WS_BYTES + 4096 + 4096;

    unsigned short* P = (unsigned short*)ws;

    if (ws_size >= NEED_MAIN) {
        unsigned short* Xs  = (unsigned short*)(ws + P_BYTES);
        unsigned short* Wsp = (unsigned short*)(ws + P_BYTES + XS_BYTES);
        float* bias    = (float*)(ws + P_BYTES + XS_BYTES + WS_BYTES);
        float* leafsum = (float*)(ws + P_BYTES + XS_BYTES + WS_BYTES + 4096);

        hipMemsetAsync(leafsum, 0, NLEAF * sizeof(float), stream);
        sdt_xsplit<<<BROWS * 100 / 256, 256, 0, stream>>>(X, Xs);
        sdt_wsplit<<<1024, 256, 0, stream>>>(Wi, Wsp, bias);
        sdt_gemm8<<<512, 512, 0, stream>>>(Xs, Wsp, bias, P);
        sdt_tree<<<BROWS / 32, 256, 0, stream>>>(P, Wl, Y, leafsum);
        sdt_penalty<<<1, 1024, 0, stream>>>(leafsum, pen);
    } else {
        // fallback: round-2 validated path (needs ~70.4 MB)
        unsigned short* Wh  = (unsigned short*)(ws + P_BYTES);
        unsigned short* Wlo = (unsigned short*)(ws + P_BYTES + 1638400);
        float* bias    = (float*)(ws + P_BYTES + 2 * 1638400);
        float* leafsum = (float*)(ws + P_BYTES + 2 * 1638400 + 4096);

        hipMemsetAsync(leafsum, 0, NLEAF * sizeof(float), stream);
        sdt_wsplit2<<<1024, 256, 0, stream>>>(Wi, Wh, Wlo, bias);
        dim3 gA(NP / 128, BROWS / 128);
        sdt_gemm_mfma<<<gA, 256, 0, stream>>>(X, Wh, Wlo, bias, P);
        sdt_tree<<<BROWS / 32, 256, 0, stream>>>(P, Wl, Y, leafsum);
        sdt_penalty<<<1, 1024, 0, stream>>>(leafsum, pen);
    }
}